// Round 1
// baseline (2498.840 us; speedup 1.0000x reference)
//
#include <hip/hip_runtime.h>
#include <math.h>

#define NNODE 10000
#define NEDGE 160000
#define KNB   16
#define K1    17
#define NT    10
#define TN    10
#define DF    128
#define CAP   64
#define NEG_BIG (-1e9f)
#define LOGQ  (-2.30258509299404568402f)

// ---------- phase 1: edge bucketing (arrival order, fixed later by select) ----------
__global__ void k_detect(const int* ei, int* flag) {
  if (blockIdx.x == 0 && threadIdx.x == 0) {
    int z = 0;
    for (int i = 0; i < 64; ++i) z |= ei[2 * i + 1];
    *flag = (z == 0) ? 1 : 0;  // 1 => int64 storage (high words all zero)
  }
}

__global__ void k_hist(const int* ei, const int* flag, int* cnt, int* ebuf) {
  int e = blockIdx.x * blockDim.x + threadIdx.x;
  if (e >= NEDGE) return;
  int wide = *flag;
  int s = wide ? ei[2 * e] : ei[e];
  int pos = atomicAdd(&cnt[s], 1);
  if (pos < CAP) ebuf[s * CAP + pos] = e;
}

// ---------- phase 2: per node, keep 16 smallest edge ids (== stable-sort order) ----------
__global__ void k_select(const int* ei, const int* flag, const int* cnt, const int* ebuf,
                         int* nbrs, int* kcnt, int* Sg) {
  int i = blockIdx.x * blockDim.x + threadIdx.x;
  if (i >= NNODE) return;
  int wide = *flag;
  int c = cnt[i]; c = c > CAP ? CAP : c;
  int best[KNB];
  int m = 0;
  for (int j = 0; j < c; ++j) {
    int e = ebuf[i * CAP + j];
    if (m < KNB) {
      int p = m++;
      while (p > 0 && best[p - 1] > e) { best[p] = best[p - 1]; --p; }
      best[p] = e;
    } else if (e < best[KNB - 1]) {
      int p = KNB - 1;
      while (p > 0 && best[p - 1] > e) { best[p] = best[p - 1]; --p; }
      best[p] = e;
    }
  }
  kcnt[i] = m;
  Sg[i * K1 + 0] = i;
  for (int j = 0; j < KNB; ++j) {
    int v = 0;
    if (j < m) {
      int e = best[j];
      v = wide ? ei[2 * (NEDGE + e)] : ei[NEDGE + e];
    }
    nbrs[i * KNB + j] = v;
    Sg[i * K1 + 1 + j] = v;
  }
}

// ---------- phase 3: local adjacency C1 [17][17] per node ----------
__global__ void k_c1(const int* nbrs, const int* kcnt, const int* Sg, float* C1g) {
  int i = blockIdx.x * blockDim.x + threadIdx.x;
  if (i >= NNODE) return;
  int S[K1];
#pragma unroll
  for (int a = 0; a < K1; ++a) S[a] = Sg[i * K1 + a];
  int kc = kcnt[i];
  for (int a = 0; a < K1; ++a) {
    float row[K1];
#pragma unroll
    for (int b = 0; b < K1; ++b) row[b] = 0.f;
    bool va = (a == 0) || (a - 1 < kc);
    if (va) {
      int u = S[a];
      int ku = kcnt[u];
      for (int j = 0; j < ku; ++j) {
        int w = nbrs[u * KNB + j];
#pragma unroll
        for (int b = 0; b < K1; ++b) {
          if (((b == 0) || (b - 1 < kc)) && (S[b] == w)) row[b] = 1.f;
        }
      }
    }
#pragma unroll
    for (int b = 0; b < K1; ++b) C1g[((size_t)i * K1 + a) * K1 + b] = row[b];
  }
}

// ---------- phase 4: template stats: ||F2[t,b]||^2 and B[t,b]=0.1*sum_c C2^2 ----------
__global__ void k_tstats(const float* tf, const float* tmpl, float* nF2, float* Bq) {
  int idx = blockIdx.x * blockDim.x + threadIdx.x;
  if (idx >= NT * TN) return;
  const float* fp = tf + (size_t)idx * DF;
  float s = 0.f;
  for (int d = 0; d < DF; ++d) { float v = fp[d]; s += v * v; }
  nF2[idx] = s;
  const float* cp = tmpl + (size_t)idx * TN;
  float s2 = 0.f;
  for (int c = 0; c < TN; ++c) { float v = cp[c]; s2 += v * v; }
  Bq[idx] = 0.1f * s2;
}

// ---------- phase 5: FGW per (node, template): half-wave per pair, lane = row ----------
__global__ void __launch_bounds__(64) k_main(
    const float* __restrict__ x, const float* __restrict__ tf,
    const float* __restrict__ tmpl,
    const int* __restrict__ kcnt, const int* __restrict__ Sg,
    const float* __restrict__ C1g,
    const float* __restrict__ nF2, const float* __restrict__ Bq,
    float* __restrict__ out)
{
  __shared__ float TpL[2][K1][TN];
  __shared__ float vL[2][K1][TN];
  __shared__ float gL[2][TN];

  const int tid = threadIdx.x;
  const int h = tid >> 5;          // half-wave = one (node,template) pair
  const int r = tid & 31;          // row slot (rows 0..16 active)
  const int B = blockIdx.x;
  const int node = B / 5;
  const int t = (B % 5) * 2 + h;   // both halves always same node (2B,2B+1 same decade)

  const bool isrow = (r < K1);
  const int kc = kcnt[node];
  const float cnt1 = (float)(1 + kc);
  const bool msk = isrow && ((r == 0) || (r - 1 < kc));
  const float inv_cnt1 = 1.f / cnt1;
  const float logp_r = msk ? -__logf(cnt1) : NEG_BIG;

  // C1 row (already mask-zeroed) and A_r = sum_c C1[r,c] * p[c]  (C1^2 == C1)
  float C1row[K1];
  float A_r = 0.f;
  if (isrow) {
    const float* c1p = C1g + ((size_t)node * K1 + r) * K1;
#pragma unroll
    for (int c = 0; c < K1; ++c) {
      float v = c1p[c];
      C1row[c] = v;
      float pc = ((c == 0) || (c - 1 < kc)) ? inv_cnt1 : 0.f;
      A_r += v * pc;
    }
  } else {
#pragma unroll
    for (int c = 0; c < K1; ++c) C1row[c] = 0.f;
  }

  float Bw[TN], M[TN];
#pragma unroll
  for (int b = 0; b < TN; ++b) {
    Bw[b] = Bq[t * TN + b];
    M[b] = nF2[t * TN + b];        // masked rows: M = ||F2_b||^2 (F1 row = 0)
  }

  // feature cost row: M[b] = ||F1_r||^2 + ||F2_b||^2 - 2 F1_r . F2_b
  if (msk) {
    const int s_node = Sg[node * K1 + r];
    const float4* xp = (const float4*)(x + (size_t)s_node * DF);
    const float4* fp = (const float4*)(tf + (size_t)t * TN * DF);
    float nF1 = 0.f;
    float dot[TN];
#pragma unroll
    for (int b = 0; b < TN; ++b) dot[b] = 0.f;
    for (int d = 0; d < DF / 4; ++d) {
      float4 a = xp[d];
      nF1 += a.x * a.x + a.y * a.y + a.z * a.z + a.w * a.w;
#pragma unroll
      for (int b = 0; b < TN; ++b) {
        float4 f2 = fp[b * (DF / 4) + d];
        dot[b] += a.x * f2.x + a.y * f2.y + a.z * f2.z + a.w * f2.w;
      }
    }
#pragma unroll
    for (int b = 0; b < TN; ++b) M[b] += nF1 - 2.f * dot[b];
  }

  // T0 = p_r * q_b  (0 on masked rows)
  float Tp[TN];
  const float pr01 = (msk ? inv_cnt1 : 0.f) * 0.1f;
#pragma unroll
  for (int b = 0; b < TN; ++b) Tp[b] = pr01;

  const float* C2p = tmpl + (size_t)t * TN * TN;
  float logK[TN], g[TN];

  for (int k = 0; k < 6; ++k) {    // 5 FW iters + final evaluation
    // cross[r,b] = (C1 . Tp . C2^T)[r,b]
    __syncthreads();
    if (isrow) {
#pragma unroll
      for (int b = 0; b < TN; ++b) TpL[h][r][b] = Tp[b];
    }
    __syncthreads();
    float tmp[TN];
#pragma unroll
    for (int d = 0; d < TN; ++d) tmp[d] = 0.f;
#pragma unroll
    for (int c = 0; c < K1; ++c) {
      float cc = C1row[c];
      if (cc != 0.f) {
#pragma unroll
        for (int d = 0; d < TN; ++d) tmp[d] += cc * TpL[h][c][d];
      }
    }
    float cross[TN];
#pragma unroll
    for (int b = 0; b < TN; ++b) {
      float s = 0.f;
#pragma unroll
      for (int d = 0; d < TN; ++d) s += tmp[d] * C2p[b * TN + d];
      cross[b] = s;
    }

    if (k == 5) {  // final: dist = 0.5*sum(M*T) + 0.5*sum(tens*T)
      float acc = 0.f;
#pragma unroll
      for (int b = 0; b < TN; ++b) {
        float tens = A_r + Bw[b] - 2.f * cross[b];
        acc += Tp[b] * (0.5f * M[b] + 0.5f * tens);
      }
#pragma unroll
      for (int mm = 16; mm >= 1; mm >>= 1) acc += __shfl_xor(acc, mm, 32);
      if (r == 0) out[node * NT + t] = acc;
      return;
    }

#pragma unroll
    for (int b = 0; b < TN; ++b) {
      float G = 0.5f * M[b] + (A_r + Bw[b] - 2.f * cross[b]);  // (1-a)M + 2a*tens, a=0.5
      logK[b] = -10.f * G;                                     // -G/REG
    }

    // log-domain Sinkhorn, 20 iters (f starts at 0 for ALL rows, like the reference)
    float f = 0.f;
    for (int it = 0; it < 20; ++it) {
      __syncthreads();
      if (isrow) {
#pragma unroll
        for (int b = 0; b < TN; ++b) vL[h][r][b] = logK[b] + f;
      }
      __syncthreads();
      if (r < TN) {  // column LSE by lanes 0..9 of each half
        float mx = -INFINITY;
#pragma unroll
        for (int a = 0; a < K1; ++a) mx = fmaxf(mx, vL[h][a][r]);
        float s = 0.f;
#pragma unroll
        for (int a = 0; a < K1; ++a) s += __expf(vL[h][a][r] - mx);
        gL[h][r] = LOGQ - (mx + __logf(s));
      }
      __syncthreads();
#pragma unroll
      for (int b = 0; b < TN; ++b) g[b] = gL[h][b];
      float mx2 = -INFINITY;
#pragma unroll
      for (int b = 0; b < TN; ++b) mx2 = fmaxf(mx2, logK[b] + g[b]);
      float s2 = 0.f;
#pragma unroll
      for (int b = 0; b < TN; ++b) s2 += __expf(logK[b] + g[b] - mx2);
      f = logp_r - (mx2 + __logf(s2));
    }

    const float gam = 2.f / ((float)k + 2.f);
#pragma unroll
    for (int b = 0; b < TN; ++b) {
      float Tn = __expf(f + g[b] + logK[b]);   // masked rows: exp(-1e9+..) = 0
      Tp[b] = (1.f - gam) * Tp[b] + gam * Tn;
    }
  }
}

extern "C" void kernel_launch(void* const* d_in, const int* in_sizes, int n_in,
                              void* d_out, int out_size, void* d_ws, size_t ws_size,
                              hipStream_t stream) {
  const float* x    = (const float*)d_in[0];
  const int*   ei   = (const int*)d_in[1];
  const float* tmpl = (const float*)d_in[2];
  const float* tf   = (const float*)d_in[3];
  float* out = (float*)d_out;

  int* cnt  = (int*)d_ws;
  int* ebuf = cnt + NNODE;
  int* nbrs = ebuf + (size_t)NNODE * CAP;
  int* kcnt = nbrs + (size_t)NNODE * KNB;
  int* Sg   = kcnt + NNODE;
  int* flag = Sg + (size_t)NNODE * K1;
  float* C1g = (float*)(flag + 256);
  float* nF2 = C1g + (size_t)NNODE * K1 * K1;
  float* Bq  = nF2 + NT * TN;

  hipMemsetAsync(cnt, 0, NNODE * sizeof(int), stream);
  k_detect<<<1, 64, 0, stream>>>(ei, flag);
  k_hist<<<(NEDGE + 255) / 256, 256, 0, stream>>>(ei, flag, cnt, ebuf);
  k_select<<<(NNODE + 255) / 256, 256, 0, stream>>>(ei, flag, cnt, ebuf, nbrs, kcnt, Sg);
  k_c1<<<(NNODE + 255) / 256, 256, 0, stream>>>(nbrs, kcnt, Sg, C1g);
  k_tstats<<<1, 128, 0, stream>>>(tf, tmpl, nF2, Bq);
  k_main<<<NNODE * 5, 64, 0, stream>>>(x, tf, tmpl, kcnt, Sg, C1g, nF2, Bq, out);
}

// Round 2
// 1185.421 us; speedup vs baseline: 2.1080x; 2.1080x over previous
//
#include <hip/hip_runtime.h>
#include <math.h>

#define NNODE 10000
#define NEDGE 160000
#define KNB   16
#define K1    17
#define NT    10
#define TN    10
#define DF    128
#define CAP   64
#define NEG_BIG (-1e9f)

// base-2 log-domain constants
#define LOG2E      1.44269504089f
#define LN2        0.69314718056f
#define LOGQ2      (-3.32192809489f)   /* log2(0.1) */
#define KB_SCALE   (-14.4269504089f)   /* -10*log2e  */
#define CR_SCALE   (28.8539008178f)    /* +20*log2e  */
#define G_SCALE    (-0.069314718056f)  /* -ln2/10    */

#if defined(__has_builtin)
#if __has_builtin(__builtin_amdgcn_exp2f)
#define EXP2F(x) __builtin_amdgcn_exp2f(x)
#endif
#endif
#ifndef EXP2F
#define EXP2F(x) __expf((x) * LN2)
#endif
#define LOG2F(x) __log2f(x)

// ---------- phase 1: edge bucketing ----------
__global__ void k_detect(const int* ei, int* flag) {
  if (blockIdx.x == 0 && threadIdx.x == 0) {
    int z = 0;
    for (int i = 0; i < 64; ++i) z |= ei[2 * i + 1];
    *flag = (z == 0) ? 1 : 0;  // 1 => int64 storage (high words all zero)
  }
}

__global__ void k_hist(const int* ei, const int* flag, int* cnt, int* ebuf) {
  int e = blockIdx.x * blockDim.x + threadIdx.x;
  if (e >= NEDGE) return;
  int wide = *flag;
  int s = wide ? ei[2 * e] : ei[e];
  int pos = atomicAdd(&cnt[s], 1);
  if (pos < CAP) ebuf[s * CAP + pos] = e;
}

// ---------- phase 2: per node, keep 16 smallest edge ids ----------
__global__ void k_select(const int* ei, const int* flag, const int* cnt, const int* ebuf,
                         int* nbrs, int* kcnt, int* Sg) {
  int i = blockIdx.x * blockDim.x + threadIdx.x;
  if (i >= NNODE) return;
  int wide = *flag;
  int c = cnt[i]; c = c > CAP ? CAP : c;
  int best[KNB];
  int m = 0;
  for (int j = 0; j < c; ++j) {
    int e = ebuf[i * CAP + j];
    if (m < KNB) {
      int p = m++;
      while (p > 0 && best[p - 1] > e) { best[p] = best[p - 1]; --p; }
      best[p] = e;
    } else if (e < best[KNB - 1]) {
      int p = KNB - 1;
      while (p > 0 && best[p - 1] > e) { best[p] = best[p - 1]; --p; }
      best[p] = e;
    }
  }
  kcnt[i] = m;
  Sg[i * K1 + 0] = i;
  for (int j = 0; j < KNB; ++j) {
    int v = 0;
    if (j < m) {
      int e = best[j];
      v = wide ? ei[2 * (NEDGE + e)] : ei[NEDGE + e];
    }
    nbrs[i * KNB + j] = v;
    Sg[i * K1 + 1 + j] = v;
  }
}

// ---------- phase 3: C1 as 17 row-bitmasks per node + A = rowsum/cnt1 ----------
__global__ void k_c1b(const int* nbrs, const int* kcnt, const int* Sg,
                      unsigned int* bitsG, float* Ag) {
  int i = blockIdx.x * blockDim.x + threadIdx.x;
  if (i >= NNODE) return;
  int S[K1];
#pragma unroll
  for (int a = 0; a < K1; ++a) S[a] = Sg[i * K1 + a];
  int kc = kcnt[i];
  float inv = 1.f / (float)(1 + kc);
  for (int a = 0; a < K1; ++a) {
    unsigned int bits = 0;
    bool va = (a == 0) || (a - 1 < kc);
    if (va) {
      int u = S[a];
      int ku = kcnt[u];
      for (int j = 0; j < ku; ++j) {
        int w = nbrs[u * KNB + j];
#pragma unroll
        for (int b = 0; b < K1; ++b) {
          if (((b == 0) || (b - 1 < kc)) && (S[b] == w)) bits |= (1u << b);
        }
      }
    }
    bitsG[i * K1 + a] = bits;
    Ag[i * K1 + a] = (float)__popc(bits) * inv;
  }
}

// ---------- phase 4: template stats ----------
__global__ void k_tstats(const float* tf, const float* tmpl, float* nF2, float* Bq) {
  int idx = blockIdx.x * blockDim.x + threadIdx.x;
  if (idx >= NT * TN) return;
  const float* fp = tf + (size_t)idx * DF;
  float s = 0.f;
  for (int d = 0; d < DF; ++d) { float v = fp[d]; s += v * v; }
  nF2[idx] = s;
  const float* cp = tmpl + (size_t)idx * TN;
  float s2 = 0.f;
  for (int c = 0; c < TN; ++c) { float v = cp[c]; s2 += v * v; }
  Bq[idx] = 0.1f * s2;
}

// ---------- phase 5: dots[i][tb] = x[i] . tf[tb]  and  nx[i] = ||x[i]||^2 ----------
__global__ void __launch_bounds__(128) k_dots(const float* __restrict__ x,
                                              const float* __restrict__ tf,
                                              float* __restrict__ dots,
                                              float* __restrict__ nxv) {
  __shared__ float xs[DF];
  int i = blockIdx.x;
  xs[threadIdx.x] = x[(size_t)i * DF + threadIdx.x];
  __syncthreads();
  int tb = threadIdx.x;
  if (tb < NT * TN) {
    const float4* fp = (const float4*)(tf + (size_t)tb * DF);
    const float4* xp = (const float4*)xs;
    float s = 0.f;
#pragma unroll
    for (int d = 0; d < DF / 4; ++d) {
      float4 a = xp[d], f = fp[d];
      s += a.x * f.x + a.y * f.y + a.z * f.z + a.w * f.w;
    }
    dots[(size_t)i * (NT * TN) + tb] = s;
  } else if (tb == NT * TN) {
    const float4* xp = (const float4*)xs;
    float s = 0.f;
#pragma unroll
    for (int d = 0; d < DF / 4; ++d) {
      float4 a = xp[d];
      s += a.x * a.x + a.y * a.y + a.z * a.z + a.w * a.w;
    }
    nxv[i] = s;
  }
}

// ---------- tree reductions ----------
__device__ __forceinline__ float tmax17(const float v[K1]) {
  float a0 = fmaxf(v[0], v[8]),  a1 = fmaxf(v[1], v[9]);
  float a2 = fmaxf(v[2], v[10]), a3 = fmaxf(v[3], v[11]);
  float a4 = fmaxf(v[4], v[12]), a5 = fmaxf(v[5], v[13]);
  float a6 = fmaxf(v[6], v[14]), a7 = fmaxf(v[7], v[15]);
  a0 = fmaxf(a0, a4); a1 = fmaxf(a1, a5); a2 = fmaxf(a2, a6); a3 = fmaxf(a3, a7);
  a0 = fmaxf(a0, a2); a1 = fmaxf(a1, a3);
  return fmaxf(fmaxf(a0, a1), v[16]);
}
__device__ __forceinline__ float tsum17(const float v[K1]) {
  float a0 = v[0] + v[8],  a1 = v[1] + v[9];
  float a2 = v[2] + v[10], a3 = v[3] + v[11];
  float a4 = v[4] + v[12], a5 = v[5] + v[13];
  float a6 = v[6] + v[14], a7 = v[7] + v[15];
  a0 += a4; a1 += a5; a2 += a6; a3 += a7;
  a0 += a2; a1 += a3;
  return (a0 + a1) + v[16];
}
__device__ __forceinline__ float tmax10(const float v[TN]) {
  float a0 = fmaxf(v[0], v[5]), a1 = fmaxf(v[1], v[6]);
  float a2 = fmaxf(v[2], v[7]), a3 = fmaxf(v[3], v[8]);
  float a4 = fmaxf(v[4], v[9]);
  return fmaxf(fmaxf(fmaxf(a0, a1), fmaxf(a2, a3)), a4);
}
__device__ __forceinline__ float tsum10(const float v[TN]) {
  float a0 = v[0] + v[5], a1 = v[1] + v[6];
  float a2 = v[2] + v[7], a3 = v[3] + v[8];
  float a4 = v[4] + v[9];
  return ((a0 + a1) + (a2 + a3)) + a4;
}

// ---------- phase 6: FGW, column-major: lane = (pair, column) ----------
__global__ void __launch_bounds__(64) k_main(
    const float* __restrict__ tmpl,
    const int* __restrict__ kcnt, const int* __restrict__ Sg,
    const unsigned int* __restrict__ bitsG, const float* __restrict__ Ag,
    const float* __restrict__ dots, const float* __restrict__ nxv,
    const float* __restrict__ nF2, const float* __restrict__ Bq,
    float* __restrict__ out)
{
  __shared__ float KT[5][20][12];   // Tp (cols) then logK, row-major, padded
  __shared__ float fL[5][20];
  __shared__ float gL[5][12];
  __shared__ float accL[5][TN];

  const int lane = threadIdx.x;
  int p = lane / 10;
  const int b = lane - p * 10;
  const bool act = (p < 5);
  if (!act) p = 4;                  // clamp for safe addressing; writes gated by act
  const int blk = blockIdx.x;
  const int node = blk >> 1;        // wave-uniform
  const int t = ((blk & 1) * 5) + p;
  const int tb = t * TN + b;

  const int kc = kcnt[node];
  const float cnt1 = (float)(1 + kc);
  const float inv_cnt1 = 1.f / cnt1;
  const float logp2v = -LOG2F(cnt1);
  const float lp2_r0 = ((b == 0) || (b - 1 < kc)) ? logp2v : NEG_BIG;  // row b
  const float lp2_r1 = ((9 + b) < kc) ? logp2v : NEG_BIG;              // row 10+b

  // C2 row b of template t (10 floats, 8B-aligned)
  float c2[TN];
  {
    const float2* cp = (const float2*)(tmpl + (size_t)tb * TN);
#pragma unroll
    for (int j = 0; j < 5; ++j) { float2 u = cp[j]; c2[2 * j] = u.x; c2[2 * j + 1] = u.y; }
  }
  const float Bb = Bq[tb];
  const float nf2b = nF2[tb];

  float Kb2[K1];           // -10*log2e * (0.5*M + A + B)
  float Tp[K1];
  unsigned int bw[K1];     // wave-uniform C1 row bitmasks (SGPRs)
#pragma unroll
  for (int a = 0; a < K1; ++a) {
    bool va = (a == 0) || (a - 1 < kc);
    int sa = Sg[node * K1 + a];
    float Ma = (va ? (nxv[sa] - 2.f * dots[(size_t)sa * (NT * TN) + tb]) : 0.f) + nf2b;
    float base = 0.5f * Ma + Ag[node * K1 + a] + Bb;
    Kb2[a] = KB_SCALE * base;
    Tp[a] = va ? (inv_cnt1 * 0.1f) : 0.f;
    bw[a] = bitsG[node * K1 + a];
  }

  float Kc2[K1], Kr0[TN], Kr1[TN], gr[TN];
  float g2 = 0.f;

#pragma unroll 1
  for (int k = 0; k < 6; ++k) {
    // ---- R = Tp @ C2^T (col b per lane) ----
    if (act) {
#pragma unroll
      for (int a = 0; a < K1; ++a) KT[p][a][b] = Tp[a];
    }
    __syncthreads();
    float R[K1];
#pragma unroll
    for (int c = 0; c < K1; ++c) {
      const float* row = &KT[p][c][0];
      float4 u0 = *(const float4*)row;
      float4 u1 = *(const float4*)(row + 4);
      float2 u2 = *(const float2*)(row + 8);
      R[c] = u0.x * c2[0] + u0.y * c2[1] + u0.z * c2[2] + u0.w * c2[3]
           + u1.x * c2[4] + u1.y * c2[5] + u1.z * c2[6] + u1.w * c2[7]
           + u2.x * c2[8] + u2.y * c2[9];
    }
    // ---- cross = C1 @ R via uniform bitmask predication; logK (base-2) ----
#pragma unroll
    for (int a = 0; a < K1; ++a) {
      float cr = 0.f;
      unsigned int m = bw[a];
      if (m) {
#pragma unroll
        for (int c = 0; c < K1; ++c)
          if (m & (1u << c)) cr += R[c];
      }
      Kc2[a] = Kb2[a] + CR_SCALE * cr;
    }

    if (k == 5) {  // dist = sum_a Tp*(0.25*M + 0.5*G), G = -ln2/10 * Kc2
      float acc = 0.f;
#pragma unroll
      for (int a = 0; a < K1; ++a) {
        bool va = (a == 0) || (a - 1 < kc);
        int sa = Sg[node * K1 + a];
        float Ma = (va ? (nxv[sa] - 2.f * dots[(size_t)sa * (NT * TN) + tb]) : 0.f) + nf2b;
        acc += Tp[a] * (0.25f * Ma + 0.5f * (G_SCALE * Kc2[a]));
      }
      if (act) accL[p][b] = acc;
      __syncthreads();
      if (lane < 5) {
        float s = 0.f;
#pragma unroll
        for (int j = 0; j < TN; ++j) s += accL[lane][j];
        out[node * NT + (blk & 1) * 5 + lane] = s;
      }
      return;
    }

    // ---- transpose logK: each lane grabs rows b and 10+b ----
    __syncthreads();
    if (act) {
#pragma unroll
      for (int a = 0; a < K1; ++a) KT[p][a][b] = Kc2[a];
    }
    __syncthreads();
    {
      const float* r0 = &KT[p][b][0];
      float4 u0 = *(const float4*)r0;
      float4 u1 = *(const float4*)(r0 + 4);
      float2 u2 = *(const float2*)(r0 + 8);
      Kr0[0] = u0.x; Kr0[1] = u0.y; Kr0[2] = u0.z; Kr0[3] = u0.w;
      Kr0[4] = u1.x; Kr0[5] = u1.y; Kr0[6] = u1.z; Kr0[7] = u1.w;
      Kr0[8] = u2.x; Kr0[9] = u2.y;
      const float* r1 = &KT[p][10 + b][0];   // rows 17..19 = padded garbage, never stored
      float4 w0 = *(const float4*)r1;
      float4 w1 = *(const float4*)(r1 + 4);
      float2 w2 = *(const float2*)(r1 + 8);
      Kr1[0] = w0.x; Kr1[1] = w0.y; Kr1[2] = w0.z; Kr1[3] = w0.w;
      Kr1[4] = w1.x; Kr1[5] = w1.y; Kr1[6] = w1.z; Kr1[7] = w1.w;
      Kr1[8] = w2.x; Kr1[9] = w2.y;
    }

    // ---- Sinkhorn: 20 iters, 2 barriers each ----
#pragma unroll 1
    for (int it = 0; it < 20; ++it) {
      float v[K1];
      if (it == 0) {
#pragma unroll
        for (int a = 0; a < K1; ++a) v[a] = Kc2[a];
      } else {
        float4 f0 = *(const float4*)&fL[p][0];
        float4 f1 = *(const float4*)&fL[p][4];
        float4 f2 = *(const float4*)&fL[p][8];
        float4 f3 = *(const float4*)&fL[p][12];
        float fx = fL[p][16];
        v[0]  = Kc2[0]  + f0.x; v[1]  = Kc2[1]  + f0.y; v[2]  = Kc2[2]  + f0.z; v[3]  = Kc2[3]  + f0.w;
        v[4]  = Kc2[4]  + f1.x; v[5]  = Kc2[5]  + f1.y; v[6]  = Kc2[6]  + f1.z; v[7]  = Kc2[7]  + f1.w;
        v[8]  = Kc2[8]  + f2.x; v[9]  = Kc2[9]  + f2.y; v[10] = Kc2[10] + f2.z; v[11] = Kc2[11] + f2.w;
        v[12] = Kc2[12] + f3.x; v[13] = Kc2[13] + f3.y; v[14] = Kc2[14] + f3.z; v[15] = Kc2[15] + f3.w;
        v[16] = Kc2[16] + fx;
      }
      float mx = tmax17(v);
#pragma unroll
      for (int a = 0; a < K1; ++a) v[a] = EXP2F(v[a] - mx);
      float s = tsum17(v);
      g2 = LOGQ2 - mx - LOG2F(s);
      if (act) gL[p][b] = g2;
      __syncthreads();
      {
        float4 g0 = *(const float4*)&gL[p][0];
        float4 g1 = *(const float4*)&gL[p][4];
        float2 gx = *(const float2*)&gL[p][8];
        gr[0] = g0.x; gr[1] = g0.y; gr[2] = g0.z; gr[3] = g0.w;
        gr[4] = g1.x; gr[5] = g1.y; gr[6] = g1.z; gr[7] = g1.w;
        gr[8] = gx.x; gr[9] = gx.y;
      }
      float w[TN], w1r[TN];
#pragma unroll
      for (int j = 0; j < TN; ++j) w[j] = Kr0[j] + gr[j];
#pragma unroll
      for (int j = 0; j < TN; ++j) w1r[j] = Kr1[j] + gr[j];
      float mxa = tmax10(w);
      float mxb = tmax10(w1r);
#pragma unroll
      for (int j = 0; j < TN; ++j) w[j] = EXP2F(w[j] - mxa);
#pragma unroll
      for (int j = 0; j < TN; ++j) w1r[j] = EXP2F(w1r[j] - mxb);
      float sa2 = tsum10(w);
      float sb2 = tsum10(w1r);
      float fr0 = lp2_r0 - mxa - LOG2F(sa2);
      float fr1 = lp2_r1 - mxb - LOG2F(sb2);
      if (act) {
        fL[p][b] = fr0;
        if (b < 7) fL[p][10 + b] = fr1;
      }
      __syncthreads();
    }

    // ---- FW update: Tp = (1-gam)*Tp + gam*exp2(f + g + logK) ----
    {
      float4 f0 = *(const float4*)&fL[p][0];
      float4 f1 = *(const float4*)&fL[p][4];
      float4 f2 = *(const float4*)&fL[p][8];
      float4 f3 = *(const float4*)&fL[p][12];
      float fx = fL[p][16];
      float fv[K1];
      fv[0]  = f0.x; fv[1]  = f0.y; fv[2]  = f0.z; fv[3]  = f0.w;
      fv[4]  = f1.x; fv[5]  = f1.y; fv[6]  = f1.z; fv[7]  = f1.w;
      fv[8]  = f2.x; fv[9]  = f2.y; fv[10] = f2.z; fv[11] = f2.w;
      fv[12] = f3.x; fv[13] = f3.y; fv[14] = f3.z; fv[15] = f3.w;
      fv[16] = fx;
      const float gam = 2.f / ((float)k + 2.f);
      const float om = 1.f - gam;
#pragma unroll
      for (int a = 0; a < K1; ++a)
        Tp[a] = om * Tp[a] + gam * EXP2F(fv[a] + g2 + Kc2[a]);
    }
  }
}

extern "C" void kernel_launch(void* const* d_in, const int* in_sizes, int n_in,
                              void* d_out, int out_size, void* d_ws, size_t ws_size,
                              hipStream_t stream) {
  const float* x    = (const float*)d_in[0];
  const int*   ei   = (const int*)d_in[1];
  const float* tmpl = (const float*)d_in[2];
  const float* tf   = (const float*)d_in[3];
  float* out = (float*)d_out;

  int* cnt  = (int*)d_ws;
  int* ebuf = cnt + NNODE;
  int* nbrs = ebuf + (size_t)NNODE * CAP;
  int* kcnt = nbrs + (size_t)NNODE * KNB;
  int* Sg   = kcnt + NNODE;
  int* flag = Sg + (size_t)NNODE * K1;
  unsigned int* bits = (unsigned int*)(flag + 256);
  float* Ag   = (float*)(bits + (size_t)NNODE * K1);
  float* dots = Ag + (size_t)NNODE * K1;
  float* nxv  = dots + (size_t)NNODE * (NT * TN);
  float* nF2  = nxv + NNODE;
  float* Bq   = nF2 + NT * TN;

  hipMemsetAsync(cnt, 0, NNODE * sizeof(int), stream);
  k_detect<<<1, 64, 0, stream>>>(ei, flag);
  k_hist<<<(NEDGE + 255) / 256, 256, 0, stream>>>(ei, flag, cnt, ebuf);
  k_select<<<(NNODE + 255) / 256, 256, 0, stream>>>(ei, flag, cnt, ebuf, nbrs, kcnt, Sg);
  k_c1b<<<(NNODE + 255) / 256, 256, 0, stream>>>(nbrs, kcnt, Sg, bits, Ag);
  k_tstats<<<1, 128, 0, stream>>>(tf, tmpl, nF2, Bq);
  k_dots<<<NNODE, 128, 0, stream>>>(x, tf, dots, nxv);
  k_main<<<NNODE * 2, 64, 0, stream>>>(tmpl, kcnt, Sg, bits, Ag, dots, nxv, nF2, Bq, out);
}